// Round 1
// baseline (2209.265 us; speedup 1.0000x reference)
//
#include <hip/hip_runtime.h>

#define NODES 50000
#define NEDGE 800000
#define FDIM  128

// Band coefficients B[i][k] = A[i][k] - A[i+1][k] (i=0..2), B[3] = A[3],
// where A[i][k] are Chebyshev-Bessel heat-kernel coeffs for tau in {0,0.5,1.5,4.0}
// (computed offline from the reference's power series; static data).
__device__ __constant__ float BCOEF[4][9] = {
  { 0.35496460f,  0.31284160f, -0.03870412f,  0.00320868f, -1.99927e-4f,
    9.97480e-6f, -4.15015e-7f,  1.48054e-8f, -4.62272e-10f },
  { 0.27760180f,  0.12523720f, -0.11205788f,  0.03283760f, -0.00637710f,
    9.58661e-4f, -1.19074e-4f,  1.26613e-5f, -1.17878e-6f },
  { 0.16043170f, -0.08057710f, -0.08449120f,  0.08620240f, -0.04530300f,
    0.01752000f, -0.00553870f,  0.00150130f, -3.58171e-4f },
  { 0.20700190f, -0.35750170f,  0.23525320f, -0.12224870f,  0.05188000f,
   -0.01848860f,  0.00565820f, -0.00151400f,  3.59350e-4f }
};

__global__ void hist_kernel(const int* __restrict__ row, int* __restrict__ cnt, int e) {
    int i = blockIdx.x * blockDim.x + threadIdx.x;
    if (i < e) atomicAdd(&cnt[row[i]], 1);
}

// single-block exclusive scan over n counts -> rowptr[0..n] (rowptr[n] = total)
__global__ void scan_kernel(const int* __restrict__ cnt, int* __restrict__ rowptr, int n) {
    __shared__ int buf[1024];
    __shared__ int carry;
    int tid = threadIdx.x;
    if (tid == 0) carry = 0;
    for (int base = 0; base < n; base += 1024) {
        int i = base + tid;
        int v = (i < n) ? cnt[i] : 0;
        __syncthreads();              // carry settled / buf free
        buf[tid] = v;
        __syncthreads();
        for (int off = 1; off < 1024; off <<= 1) {
            int t = (tid >= off) ? buf[tid - off] : 0;
            __syncthreads();
            buf[tid] += t;
            __syncthreads();
        }
        int incl = buf[tid];
        int c = carry;
        if (i < n) rowptr[i] = c + incl - v;   // exclusive
        __syncthreads();              // everyone read carry
        if (tid == 1023) carry = c + incl;
    }
    __syncthreads();
    if (tid == 0) rowptr[n] = carry;
}

__global__ void scatter_kernel(const int* __restrict__ row, const int* __restrict__ col,
                               const float* __restrict__ w, int* __restrict__ cursor,
                               int* __restrict__ ccol, float* __restrict__ cw, int e) {
    int i = blockIdx.x * blockDim.x + threadIdx.x;
    if (i < e) {
        int r = row[i];
        int pos = atomicAdd(&cursor[r], 1);
        ccol[pos] = col[i];
        cw[pos]  = w[i];
    }
}

// pout[row][f] = alpha * sum_e w_e * pin[col_e][f]  (- psub[row][f] if psub)
// 128 threads per row (thread = feature), 2 rows per 256-thread block.
__global__ __launch_bounds__(256) void spmm_kernel(
    const int* __restrict__ rowptr, const int* __restrict__ cols,
    const float* __restrict__ wts, const float* __restrict__ pin,
    const float* __restrict__ psub, float* __restrict__ pout,
    float alpha, int n)
{
    int row = blockIdx.x * 2 + (threadIdx.x >> 7);
    int f   = threadIdx.x & 127;
    if (row >= n) return;
    int s = rowptr[row], e = rowptr[row + 1];
    float acc = 0.f;
    for (int i = s; i < e; ++i) {
        int   c = cols[i];
        float w = wts[i];
        acc += w * pin[(size_t)c * FDIM + f];
    }
    float r = alpha * acc;
    if (psub) r -= psub[(size_t)row * FDIM + f];
    pout[(size_t)row * FDIM + f] = r;
}

// Per 16-node tile: bands -> LDS, per-band GEMM+ReLU (reusing the same LDS
// slot per band), then the 640x128 fuse GEMM.
__global__ __launch_bounds__(256) void fuse_kernel(
    const float* __restrict__ X,        // Psi_0  [N][128]
    const float* __restrict__ psi,      // Psi_1..8  [8][N][128]
    const float* __restrict__ W_band,   // [4][128][128]
    const float* __restrict__ b_band,   // [4][128]
    const float* __restrict__ W_fuse,   // [640][128]
    const float* __restrict__ b_fuse,   // [128]
    float* __restrict__ out)            // [N][128]
{
    __shared__ float buf[4][16][129];   // 33 KB; bands then reused for H
    const int tid = threadIdx.x;
    const int n0  = blockIdx.x * 16;

    // Phase 1: bands[i][node][f] = sum_k B[i][k] * Psi_k[node][f]
    for (int idx = tid; idx < 16 * 128; idx += 256) {
        int nl = idx >> 7, f = idx & 127;
        size_t node = (size_t)(n0 + nl);
        float p[9];
        p[0] = X[node * FDIM + f];
#pragma unroll
        for (int k = 0; k < 8; ++k)
            p[k + 1] = psi[((size_t)k * NODES + node) * FDIM + f];
#pragma unroll
        for (int i = 0; i < 4; ++i) {
            float v = 0.f;
#pragma unroll
            for (int k = 0; k < 9; ++k) v += BCOEF[i][k] * p[k];
            buf[i][nl][f] = v;
        }
    }
    __syncthreads();

    const int node = tid >> 4;   // 0..15
    const int oc   = tid & 15;   // 0..15 -> output chunk of 8
    const int o8   = oc * 8;

    // Phase 2: H_i = relu(bands_i @ W_band_i + b_i), written back over bands_i
    for (int i = 0; i < 4; ++i) {
        float acc[8];
#pragma unroll
        for (int j = 0; j < 8; ++j) acc[j] = 0.f;
        const float4* Wb4 = reinterpret_cast<const float4*>(W_band) + (size_t)i * 128 * 32;
        for (int f = 0; f < 128; ++f) {
            float b  = buf[i][node][f];
            float4 w0 = Wb4[f * 32 + oc * 2];
            float4 w1 = Wb4[f * 32 + oc * 2 + 1];
            acc[0] += b * w0.x; acc[1] += b * w0.y; acc[2] += b * w0.z; acc[3] += b * w0.w;
            acc[4] += b * w1.x; acc[5] += b * w1.y; acc[6] += b * w1.z; acc[7] += b * w1.w;
        }
        __syncthreads();   // all reads of bands_i done before overwrite
#pragma unroll
        for (int j = 0; j < 8; ++j) {
            float hv = acc[j] + b_band[i * 128 + o8 + j];
            buf[i][node][o8 + j] = hv > 0.f ? hv : 0.f;
        }
    }
    __syncthreads();

    // Phase 3: out[node][o] = b_fuse[o] + sum_p H[p]*Wf[p][o] + sum_f X[f]*Wf[512+f][o]
    float acc[8];
#pragma unroll
    for (int j = 0; j < 8; ++j) acc[j] = b_fuse[o8 + j];
    const float4* Wf4 = reinterpret_cast<const float4*>(W_fuse);
    for (int p = 0; p < 512; ++p) {
        float hv = buf[p >> 7][node][p & 127];
        float4 w0 = Wf4[p * 32 + oc * 2];
        float4 w1 = Wf4[p * 32 + oc * 2 + 1];
        acc[0] += hv * w0.x; acc[1] += hv * w0.y; acc[2] += hv * w0.z; acc[3] += hv * w0.w;
        acc[4] += hv * w1.x; acc[5] += hv * w1.y; acc[6] += hv * w1.z; acc[7] += hv * w1.w;
    }
    const float* xrow = X + (size_t)(n0 + node) * FDIM;
    for (int f = 0; f < 128; ++f) {
        float xv = xrow[f];
        float4 w0 = Wf4[(512 + f) * 32 + oc * 2];
        float4 w1 = Wf4[(512 + f) * 32 + oc * 2 + 1];
        acc[0] += xv * w0.x; acc[1] += xv * w0.y; acc[2] += xv * w0.z; acc[3] += xv * w0.w;
        acc[4] += xv * w1.x; acc[5] += xv * w1.y; acc[6] += xv * w1.z; acc[7] += xv * w1.w;
    }
    float4* orow = reinterpret_cast<float4*>(out + (size_t)(n0 + node) * FDIM);
    orow[oc * 2]     = make_float4(acc[0], acc[1], acc[2], acc[3]);
    orow[oc * 2 + 1] = make_float4(acc[4], acc[5], acc[6], acc[7]);
}

extern "C" void kernel_launch(void* const* d_in, const int* in_sizes, int n_in,
                              void* d_out, int out_size, void* d_ws, size_t ws_size,
                              hipStream_t stream) {
    (void)in_sizes; (void)n_in; (void)out_size;
    const float* X      = (const float*)d_in[0];
    const int*   erow   = (const int*)d_in[1];
    const int*   ecol   = (const int*)d_in[2];
    const float* ew     = (const float*)d_in[3];
    const float* W_band = (const float*)d_in[4];
    const float* b_band = (const float*)d_in[5];
    const float* W_fuse = (const float*)d_in[6];
    const float* b_fuse = (const float*)d_in[7];
    float* out = (float*)d_out;

    // workspace layout (~212 MB)
    float* psi    = (float*)d_ws;                        // 8*N*128 f32
    int*   rowptr = (int*)(psi + (size_t)8 * NODES * FDIM); // N+1
    int*   cursor = rowptr + NODES + 1;                  // N
    int*   ccol   = cursor + NODES;                      // E
    float* cw     = (float*)(ccol + NEDGE);              // E
    size_t needed = ((size_t)8 * NODES * FDIM + NODES + 1 + NODES) * 4
                  + (size_t)NEDGE * 8;
    if (ws_size < needed) return;  // would corrupt; fail loudly via wrong output

    // CSR build
    hipMemsetAsync(cursor, 0, NODES * sizeof(int), stream);
    hist_kernel<<<(NEDGE + 255) / 256, 256, 0, stream>>>(erow, cursor, NEDGE);
    scan_kernel<<<1, 1024, 0, stream>>>(cursor, rowptr, NODES);
    hipMemcpyAsync(cursor, rowptr, NODES * sizeof(int), hipMemcpyDeviceToDevice, stream);
    scatter_kernel<<<(NEDGE + 255) / 256, 256, 0, stream>>>(erow, ecol, ew, cursor, ccol, cw, NEDGE);

    // Chebyshev recurrence: Psi_1 = S X ; Psi_k = 2 S Psi_{k-1} - Psi_{k-2}
    spmm_kernel<<<NODES / 2, 256, 0, stream>>>(rowptr, ccol, cw, X, nullptr, psi, 1.0f, NODES);
    for (int k = 2; k <= 8; ++k) {
        const float* pin  = psi + (size_t)(k - 2) * NODES * FDIM;
        const float* psub = (k == 2) ? X : psi + (size_t)(k - 3) * NODES * FDIM;
        float*       pout = psi + (size_t)(k - 1) * NODES * FDIM;
        spmm_kernel<<<NODES / 2, 256, 0, stream>>>(rowptr, ccol, cw, pin, psub, pout, 2.0f, NODES);
    }

    // bands + band GEMMs + fuse GEMM
    fuse_kernel<<<NODES / 16, 256, 0, stream>>>(X, psi, W_band, b_band, W_fuse, b_fuse, out);
}

// Round 2
// 754.266 us; speedup vs baseline: 2.9290x; 2.9290x over previous
//
#include <hip/hip_runtime.h>

#define NODES 50000
#define NEDGE 800000
#define FDIM  128

typedef __bf16 bf16x8 __attribute__((ext_vector_type(8)));
typedef float  f32x4  __attribute__((ext_vector_type(4)));

// Band coefficients B[i][k] = A[i][k] - A[i+1][k] (i=0..2), B[3] = A[3] (verified round 1).
__device__ __constant__ float BCOEF[4][9] = {
  { 0.35496460f,  0.31284160f, -0.03870412f,  0.00320868f, -1.99927e-4f,
    9.97480e-6f, -4.15015e-7f,  1.48054e-8f, -4.62272e-10f },
  { 0.27760180f,  0.12523720f, -0.11205788f,  0.03283760f, -0.00637710f,
    9.58661e-4f, -1.19074e-4f,  1.26613e-5f, -1.17878e-6f },
  { 0.16043170f, -0.08057710f, -0.08449120f,  0.08620240f, -0.04530300f,
    0.01752000f, -0.00553870f,  0.00150130f, -3.58171e-4f },
  { 0.20700190f, -0.35750170f,  0.23525320f, -0.12224870f,  0.05188000f,
   -0.01848860f,  0.00565820f, -0.00151400f,  3.59350e-4f }
};

__global__ void hist_kernel(const int* __restrict__ row, int* __restrict__ cnt, int e) {
    int i = blockIdx.x * blockDim.x + threadIdx.x;
    if (i < e) atomicAdd(&cnt[row[i]], 1);
}

__global__ void scan_kernel(const int* __restrict__ cnt, int* __restrict__ rowptr, int n) {
    __shared__ int buf[1024];
    __shared__ int carry;
    int tid = threadIdx.x;
    if (tid == 0) carry = 0;
    for (int base = 0; base < n; base += 1024) {
        int i = base + tid;
        int v = (i < n) ? cnt[i] : 0;
        __syncthreads();
        buf[tid] = v;
        __syncthreads();
        for (int off = 1; off < 1024; off <<= 1) {
            int t = (tid >= off) ? buf[tid - off] : 0;
            __syncthreads();
            buf[tid] += t;
            __syncthreads();
        }
        int incl = buf[tid];
        int c = carry;
        if (i < n) rowptr[i] = c + incl - v;
        __syncthreads();
        if (tid == 1023) carry = c + incl;
    }
    __syncthreads();
    if (tid == 0) rowptr[n] = carry;
}

__global__ void scatter_kernel(const int* __restrict__ row, const int* __restrict__ col,
                               const float* __restrict__ w, int* __restrict__ cursor,
                               int* __restrict__ ccol, float* __restrict__ cw, int e) {
    int i = blockIdx.x * blockDim.x + threadIdx.x;
    if (i < e) {
        int r = row[i];
        int pos = atomicAdd(&cursor[r], 1);
        ccol[pos] = col[i];
        cw[pos]  = w[i];
    }
}

// wave-per-row SpMM: lane holds features (2*lane, 2*lane+1); edge loop unrolled x4
// for 4 outstanding gathers (was 1 -> latency-bound at ~160us/dispatch).
__global__ __launch_bounds__(256) void spmm2(
    const int* __restrict__ rowptr, const int* __restrict__ cols,
    const float* __restrict__ wts, const float* __restrict__ pin,
    const float* __restrict__ psub, float* __restrict__ pout,
    float alpha, int n)
{
    int row = blockIdx.x * 4 + (threadIdx.x >> 6);
    if (row >= n) return;
    int lane = threadIdx.x & 63;
    int s = rowptr[row], e = rowptr[row + 1];
    const float2* pin2 = reinterpret_cast<const float2*>(pin);
    float ax0 = 0.f, ay0 = 0.f, ax1 = 0.f, ay1 = 0.f;
    float ax2 = 0.f, ay2 = 0.f, ax3 = 0.f, ay3 = 0.f;
    int i = s;
    for (; i + 4 <= e; i += 4) {
        int c0 = cols[i], c1 = cols[i + 1], c2 = cols[i + 2], c3 = cols[i + 3];
        float w0 = wts[i], w1 = wts[i + 1], w2 = wts[i + 2], w3 = wts[i + 3];
        float2 v0 = pin2[(size_t)c0 * 64 + lane];
        float2 v1 = pin2[(size_t)c1 * 64 + lane];
        float2 v2 = pin2[(size_t)c2 * 64 + lane];
        float2 v3 = pin2[(size_t)c3 * 64 + lane];
        ax0 += w0 * v0.x; ay0 += w0 * v0.y;
        ax1 += w1 * v1.x; ay1 += w1 * v1.y;
        ax2 += w2 * v2.x; ay2 += w2 * v2.y;
        ax3 += w3 * v3.x; ay3 += w3 * v3.y;
    }
    for (; i < e; ++i) {
        int c = cols[i]; float wv = wts[i];
        float2 v = pin2[(size_t)c * 64 + lane];
        ax0 += wv * v.x; ay0 += wv * v.y;
    }
    float rx = alpha * ((ax0 + ax1) + (ax2 + ax3));
    float ry = alpha * ((ay0 + ay1) + (ay2 + ay3));
    size_t off = (size_t)row * 64 + lane;
    if (psub) {
        float2 sv = reinterpret_cast<const float2*>(psub)[off];
        rx -= sv.x; ry -= sv.y;
    }
    reinterpret_cast<float2*>(pout)[off] = make_float2(rx, ry);
}

// ---------------- MFMA epilogue ----------------
// LDS map (16B chunks): slots 0..3 = bands_i -> H_i [32][128] bf16, slot 4 = X bf16,
// then Wt (transposed weights) [128 o][128 k] bf16. XOR swizzle c ^= (row&15) makes
// all ds_read_b128 fragment reads <=2-way bank aliased (free per m136).
#define RIDX(s, r, c) ((((s) << 9) + ((r) << 4) + ((c) ^ ((r) & 15))) << 3)
#define WIDX(o, c)    (((2560 + ((o) << 4) + ((c) ^ ((o) & 15)))) << 3)

__device__ __forceinline__ void stage_wt(const float* __restrict__ Wsrc, __bf16* SW) {
    // Wsrc: [128 k][128 o] f32 row-major -> LDS Wt[o][k] bf16 (swizzled)
    for (int it = 0; it < 8; ++it) {
        int task = it * 256 + threadIdx.x;   // 0..2047
        int o = task & 127, c = task >> 7;   // chunk c covers k = c*8..c*8+7
        const float* colp = Wsrc + (size_t)(c * 8) * 128 + o;
        bf16x8 v;
#pragma unroll
        for (int j = 0; j < 8; ++j) v[j] = (__bf16)colp[(size_t)j * 128];
        *reinterpret_cast<bf16x8*>(&SW[WIDX(o, c)]) = v;
    }
}

__global__ __launch_bounds__(256) void epilogue_kernel(
    const float* __restrict__ X,        // [N][128]
    const float* __restrict__ psi,      // [8][N][128]
    const float* __restrict__ W_band,   // [4][128][128]
    const float* __restrict__ b_band,   // [4][128]
    const float* __restrict__ W_fuse,   // [640][128]
    const float* __restrict__ b_fuse,   // [128]
    float* __restrict__ out)            // [N][128]
{
    __shared__ __align__(16) __bf16 SW[36864];   // 72 KB -> 2 blocks/CU
    const int tid = threadIdx.x;
    const int n0 = blockIdx.x * 32;

    // Phase 1: bands (f32 combine of 9 Psi arrays) -> bf16 LDS; X -> bf16 LDS slot 4.
    for (int t = tid; t < 512; t += 256) {
        int row = t >> 4, c = t & 15;
        int node = n0 + row;
        bool ok = node < NODES;
        float bacc[4][8];
#pragma unroll
        for (int i = 0; i < 4; ++i)
#pragma unroll
            for (int j = 0; j < 8; ++j) bacc[i][j] = 0.f;
#pragma unroll
        for (int k = 0; k <= 8; ++k) {
            const float* src = (k == 0)
                ? X + (size_t)node * FDIM + c * 8
                : psi + ((size_t)(k - 1) * NODES + node) * FDIM + c * 8;
            float4 q0 = make_float4(0.f, 0.f, 0.f, 0.f), q1 = q0;
            if (ok) {
                q0 = reinterpret_cast<const float4*>(src)[0];
                q1 = reinterpret_cast<const float4*>(src)[1];
            }
            float pk[8] = {q0.x, q0.y, q0.z, q0.w, q1.x, q1.y, q1.z, q1.w};
            if (k == 0) {
                bf16x8 xv;
#pragma unroll
                for (int j = 0; j < 8; ++j) xv[j] = (__bf16)pk[j];
                *reinterpret_cast<bf16x8*>(&SW[RIDX(4, row, c)]) = xv;
            }
#pragma unroll
            for (int i = 0; i < 4; ++i)
#pragma unroll
                for (int j = 0; j < 8; ++j) bacc[i][j] += BCOEF[i][k] * pk[j];
        }
#pragma unroll
        for (int i = 0; i < 4; ++i) {
            bf16x8 bv;
#pragma unroll
            for (int j = 0; j < 8; ++j) bv[j] = (__bf16)bacc[i][j];
            *reinterpret_cast<bf16x8*>(&SW[RIDX(i, row, c)]) = bv;
        }
    }

    const int l  = tid & 63, w = tid >> 6;
    const int lo = l & 15, hi = l >> 4;
    const int m  = w & 1, nb = (w >> 1) * 4;   // wave -> (M-tile, 4 N-tiles)

    // Phase 2: per-band GEMM H_i = relu(bands_i @ W_i + b_i), H_i overwrites bands_i.
    for (int i = 0; i < 4; ++i) {
        __syncthreads();                       // R_i ready / prev Wt reads done
        stage_wt(W_band + (size_t)i * 128 * 128, SW);
        __syncthreads();
        f32x4 hacc[4];
#pragma unroll
        for (int n = 0; n < 4; ++n) hacc[n] = (f32x4){0.f, 0.f, 0.f, 0.f};
#pragma unroll
        for (int k = 0; k < 4; ++k) {
            bf16x8 a = *reinterpret_cast<const bf16x8*>(&SW[RIDX(i, m * 16 + lo, k * 4 + hi)]);
#pragma unroll
            for (int n = 0; n < 4; ++n) {
                bf16x8 b = *reinterpret_cast<const bf16x8*>(&SW[WIDX((nb + n) * 16 + lo, k * 4 + hi)]);
                hacc[n] = __builtin_amdgcn_mfma_f32_16x16x32_bf16(a, b, hacc[n], 0, 0, 0);
            }
        }
        __syncthreads();                       // all reads of R_i done before overwrite
#pragma unroll
        for (int n = 0; n < 4; ++n) {
            float bb = b_band[i * 128 + (nb + n) * 16 + lo];
#pragma unroll
            for (int r = 0; r < 4; ++r) {
                float h = hacc[n][r] + bb;
                h = h > 0.f ? h : 0.f;
                int row = m * 16 + hi * 4 + r;
                int o   = (nb + n) * 16 + lo;
                SW[((i << 9) + (row << 4) + (((o >> 3)) ^ (row & 15))) * 8 + (o & 7)] = (__bf16)h;
            }
        }
    }

    // Phase 3: fuse GEMM over K=640 = slots {H0,H1,H2,H3,X} x 128.
    f32x4 facc[4];
#pragma unroll
    for (int n = 0; n < 4; ++n) facc[n] = (f32x4){0.f, 0.f, 0.f, 0.f};
    for (int kc = 0; kc < 5; ++kc) {
        __syncthreads();                       // prev Wt reads / H writes done
        stage_wt(W_fuse + (size_t)kc * 128 * 128, SW);
        __syncthreads();
#pragma unroll
        for (int k = 0; k < 4; ++k) {
            bf16x8 a = *reinterpret_cast<const bf16x8*>(&SW[RIDX(kc, m * 16 + lo, k * 4 + hi)]);
#pragma unroll
            for (int n = 0; n < 4; ++n) {
                bf16x8 b = *reinterpret_cast<const bf16x8*>(&SW[WIDX((nb + n) * 16 + lo, k * 4 + hi)]);
                facc[n] = __builtin_amdgcn_mfma_f32_16x16x32_bf16(a, b, facc[n], 0, 0, 0);
            }
        }
    }
#pragma unroll
    for (int n = 0; n < 4; ++n) {
        float bf = b_fuse[(nb + n) * 16 + lo];
#pragma unroll
        for (int r = 0; r < 4; ++r) {
            int node = n0 + m * 16 + hi * 4 + r;
            if (node < NODES)
                out[(size_t)node * FDIM + (nb + n) * 16 + lo] = facc[n][r] + bf;
        }
    }
}

extern "C" void kernel_launch(void* const* d_in, const int* in_sizes, int n_in,
                              void* d_out, int out_size, void* d_ws, size_t ws_size,
                              hipStream_t stream) {
    (void)in_sizes; (void)n_in; (void)out_size;
    const float* X      = (const float*)d_in[0];
    const int*   erow   = (const int*)d_in[1];
    const int*   ecol   = (const int*)d_in[2];
    const float* ew     = (const float*)d_in[3];
    const float* W_band = (const float*)d_in[4];
    const float* b_band = (const float*)d_in[5];
    const float* W_fuse = (const float*)d_in[6];
    const float* b_fuse = (const float*)d_in[7];
    float* out = (float*)d_out;

    float* psi    = (float*)d_ws;                           // 8*N*128 f32
    int*   rowptr = (int*)(psi + (size_t)8 * NODES * FDIM); // N+1
    int*   cursor = rowptr + NODES + 1;                     // N
    int*   ccol   = cursor + NODES;                         // E
    float* cw     = (float*)(ccol + NEDGE);                 // E
    size_t needed = ((size_t)8 * NODES * FDIM + NODES + 1 + NODES) * 4
                  + (size_t)NEDGE * 8;
    if (ws_size < needed) return;

    // CSR build
    hipMemsetAsync(cursor, 0, NODES * sizeof(int), stream);
    hist_kernel<<<(NEDGE + 255) / 256, 256, 0, stream>>>(erow, cursor, NEDGE);
    scan_kernel<<<1, 1024, 0, stream>>>(cursor, rowptr, NODES);
    hipMemcpyAsync(cursor, rowptr, NODES * sizeof(int), hipMemcpyDeviceToDevice, stream);
    scatter_kernel<<<(NEDGE + 255) / 256, 256, 0, stream>>>(erow, ecol, ew, cursor, ccol, cw, NEDGE);

    // Chebyshev recurrence: Psi_1 = S X ; Psi_k = 2 S Psi_{k-1} - Psi_{k-2}
    spmm2<<<NODES / 4, 256, 0, stream>>>(rowptr, ccol, cw, X, nullptr, psi, 1.0f, NODES);
    for (int k = 2; k <= 8; ++k) {
        const float* pin  = psi + (size_t)(k - 2) * NODES * FDIM;
        const float* psub = (k == 2) ? X : psi + (size_t)(k - 3) * NODES * FDIM;
        float*       pout = psi + (size_t)(k - 1) * NODES * FDIM;
        spmm2<<<NODES / 4, 256, 0, stream>>>(rowptr, ccol, cw, pin, psub, pout, 2.0f, NODES);
    }

    // bands + band GEMMs + fuse GEMM (bf16 MFMA, f32 accum)
    epilogue_kernel<<<(NODES + 31) / 32, 256, 0, stream>>>(
        X, psi, W_band, b_band, W_fuse, b_fuse, out);
}